// Round 15
// baseline (57.294 us; speedup 1.0000x reference)
//
#include <hip/hip_runtime.h>

typedef float v2f __attribute__((ext_vector_type(2)));

constexpr int WIDTH  = 96;
constexpr int HEIGHT = 72;
constexpr int NPTS   = WIDTH * HEIGHT;   // 6912

constexpr int BLOCK  = 128;

// ---- full (asymmetric) phase FIRST (longer blocks): s2, s4 ----
constexpr int NTILE  = 768;              // n-points per block (6/thread, 3 v2f)
constexpr int MTILE  = 64;               // m-points per block
constexpr int NTB    = NPTS / NTILE;     // 9
constexpr int MTB    = NPTS / MTILE;     // 108
constexpr int NBF    = NTB * MTB;        // 972 full blocks

// ---- triangle (symmetric) phase: s0, s1, s3 ----
constexpr int TT     = 384;              // square tile edge (3 pts/thread)
constexpr int T      = NPTS / TT;        // 18
constexpr int NPAIR  = T * (T + 1) / 2;  // 171 tile-pairs
constexpr int MCH    = 64;               // m-rows per block
constexpr int NCHT   = TT / MCH;         // 6 chunks per pair
constexpr int NBT    = NPAIR * NCHT;     // 1026 triangle blocks

constexpr int NBLK   = NBF + NBT;        // 1998 total

constexpr int ROWT   = 20;               // triangle table row (80 B)
constexpr int ROWFN  = 8;                // full n-side row (32 B)
constexpr int ROWFM  = 12;               // full m-side row (48 B)

// exp(-0.1*d) = exp2(d * KEXP)
constexpr float KEXP  = -0.14426950408889634f;  // -0.1 * log2(e)
constexpr float M2K   = -2.0f * KEXP;

// QT row: 0..2 xyz1, 3 K|xyz1|^2 | 4..6 xyz2_t, 7 K|..|^2 |
//         8..10 xyz2_gt, 11 K|..|^2 | 12..14 f1, 15..17 f2, 18..19 pad
// QFn row: 0..2 M2K*xyz1, 3 K|xyz1|^2, 4..6 f1, 7 pad
// QFm row: 0..2 xyz2_t, 3 K|..|^2, 4..6 xyz2_gt, 7 K|..|^2, 8..10 f2, 11 pad
__global__ __launch_bounds__(256) void precompute_kernel(
    const float* __restrict__ depth1, const float* __restrict__ depth2,
    const float* __restrict__ pose,   const float* __restrict__ img1,
    const float* __restrict__ img2,   const float* __restrict__ poseg,
    float* __restrict__ QT, float* __restrict__ QFn, float* __restrict__ QFm)
{
    const int idx = blockIdx.x * 256 + threadIdx.x;

    float R[12], G[12];
#pragma unroll
    for (int i = 0; i < 12; ++i) { R[i] = pose[i]; G[i] = poseg[i]; }

    const int u = idx % WIDTH;
    const int v = idx / WIDTH;
    const float gy = (float)u * (1.0f / 48.0f) - 1.0f;
    const float gz = (float)v * (1.0f / 36.0f) - 1.0f;
    const float d1 = depth1[idx];
    const float d2 = depth2[idx];
    const float x1 = d1, y1 = d1 * gy, z1 = d1 * gz;
    const float x2 = d2, y2 = d2 * gy, z2 = d2 * gz;
    const float xt = R[0] * x2 + R[1] * y2 + R[2]  * z2 + R[3];
    const float yt = R[4] * x2 + R[5] * y2 + R[6]  * z2 + R[7];
    const float zt = R[8] * x2 + R[9] * y2 + R[10] * z2 + R[11];
    const float xg = G[0] * x2 + G[1] * y2 + G[2]  * z2 + G[3];
    const float yg = G[4] * x2 + G[5] * y2 + G[6]  * z2 + G[7];
    const float zg = G[8] * x2 + G[9] * y2 + G[10] * z2 + G[11];

    const float q1 = KEXP * (x1*x1 + y1*y1 + z1*z1);
    const float qt = KEXP * (xt*xt + yt*yt + zt*zt);
    const float qg = KEXP * (xg*xg + yg*yg + zg*zg);
    const float f1a = img1[idx], f1b = img1[NPTS + idx], f1c = img1[2*NPTS + idx];
    const float f2a = img2[idx], f2b = img2[NPTS + idx], f2c = img2[2*NPTS + idx];

    float4* qt_row = (float4*)(QT + (size_t)idx * ROWT);
    qt_row[0] = make_float4(x1, y1, z1, q1);
    qt_row[1] = make_float4(xt, yt, zt, qt);
    qt_row[2] = make_float4(xg, yg, zg, qg);
    qt_row[3] = make_float4(f1a, f1b, f1c, f2a);
    qt_row[4] = make_float4(f2b, f2c, 0.f, 0.f);

    float4* fn_row = (float4*)(QFn + (size_t)idx * ROWFN);
    fn_row[0] = make_float4(M2K * x1, M2K * y1, M2K * z1, q1);
    fn_row[1] = make_float4(f1a, f1b, f1c, 0.f);

    float4* fm_row = (float4*)(QFm + (size_t)idx * ROWFM);
    fm_row[0] = make_float4(xt, yt, zt, qt);
    fm_row[1] = make_float4(xg, yg, zg, qg);
    fm_row[2] = make_float4(f2a, f2b, f2c, 0.f);
}

__global__ __launch_bounds__(BLOCK, 4) void pair_kernel(
    const float* __restrict__ QT,  const float* __restrict__ QFn,
    const float* __restrict__ QFm,
    float* __restrict__ pT, float* __restrict__ pF)
{
    __shared__ float red[2][3];
    const int t = threadIdx.x;

    // opaque per-lane zero: defeats uniformity analysis so b-row loads go
    // down the VMEM path (deep miss queues, vmcnt pipelining, L1 reuse)
    int vz;
    asm("v_mov_b32 %0, 0" : "=v"(vz));

    if (blockIdx.x < NBF) {
        // ------ full phase: s2, s4  (6 n-pts/thread = 3 v2f sets) ------
        const int blk = blockIdx.x;
        const int bn = blk % NTB;
        const int bm = blk / NTB;

        v2f A[3][7];   // per set: 0..2 M2K*xyz1, 3 K|xyz1|^2, 4..6 f1
#pragma unroll
        for (int s = 0; s < 3; ++s) {
            const int n0 = bn * NTILE + s * (2 * BLOCK) + t;
            const float4* r0 = (const float4*)(QFn + (size_t)n0 * ROWFN);
            const float4* r1 = (const float4*)(QFn + (size_t)(n0 + BLOCK) * ROWFN);
            const float4 a0 = r0[0], a1 = r0[1];
            const float4 c0 = r1[0], c1 = r1[1];
            A[s][0].x=a0.x; A[s][0].y=c0.x;  A[s][1].x=a0.y; A[s][1].y=c0.y;
            A[s][2].x=a0.z; A[s][2].y=c0.z;  A[s][3].x=a0.w; A[s][3].y=c0.w;
            A[s][4].x=a1.x; A[s][4].y=c1.x;  A[s][5].x=a1.y; A[s][5].y=c1.y;
            A[s][6].x=a1.z; A[s][6].y=c1.z;
        }

        v2f s2v[3], s4v[3];
#pragma unroll
        for (int s = 0; s < 3; ++s) { s2v[s] = v2f{0.f, 0.f}; s4v[s] = v2f{0.f, 0.f}; }

        const float* __restrict__ qv =
            QFm + (size_t)(bm * MTILE) * ROWFM + vz;   // per-lane (same) addr
#pragma unroll 2
        for (int m = 0; m < MTILE; ++m) {
            const float4* bp = (const float4*)(qv + (size_t)m * ROWFM);
            const float4 B0 = bp[0], B1 = bp[1], B2 = bp[2];
            const float b0=B0.x, b1=B0.y, b2=B0.z, b3=B0.w;
            const float b4=B1.x, b5=B1.y, b6=B1.z, b7=B1.w;
            const float b8=B2.x, b9=B2.y, b10=B2.z;
#pragma unroll
            for (int s = 0; s < 3; ++s) {
                v2f t12 = A[s][3] + b3;
                t12 = A[s][0] * b0 + t12;
                t12 = A[s][1] * b1 + t12;
                t12 = A[s][2] * b2 + t12;
                v2f t1g = A[s][3] + b7;
                t1g = A[s][0] * b4 + t1g;
                t1g = A[s][1] * b5 + t1g;
                t1g = A[s][2] * b6 + t1g;
                v2f g12 = A[s][4] * b8;
                g12 = A[s][5] * b9  + g12;
                g12 = A[s][6] * b10 + g12;
                v2f e12, e1g;
                e12.x = __builtin_amdgcn_exp2f(t12.x);
                e12.y = __builtin_amdgcn_exp2f(t12.y);
                e1g.x = __builtin_amdgcn_exp2f(t1g.x);
                e1g.y = __builtin_amdgcn_exp2f(t1g.y);
                s2v[s] = e12 * g12 + s2v[s];
                s4v[s] = e1g * g12 + s4v[s];
            }
        }

        float r2 = s2v[0].x + s2v[0].y + s2v[1].x + s2v[1].y + s2v[2].x + s2v[2].y;
        float r4 = s4v[0].x + s4v[0].y + s4v[1].x + s4v[1].y + s4v[2].x + s4v[2].y;
#pragma unroll
        for (int off = 32; off > 0; off >>= 1) {
            r2 += __shfl_down(r2, off);
            r4 += __shfl_down(r4, off);
        }
        const int wave = t >> 6, lane = t & 63;
        if (lane == 0) { red[wave][0] = r2; red[wave][1] = r4; }
        __syncthreads();
        if (t == 0) {
            pF[0 * NBF + blk] = red[0][0] + red[1][0];
            pF[1 * NBF + blk] = red[0][1] + red[1][1];
        }
    } else {
        // ------ triangle phase: s0, s1, s3  (3 n-pts/thread: v2f + scalar) ------
        const int tb    = blockIdx.x - NBF;
        const int pair  = tb / NCHT;
        const int chunk = tb % NCHT;
        int rem = pair, i = 0;
        while (rem >= T - i) { rem -= T - i; ++i; }   // uniform, <=18 iters
        const int j = i + rem;

        v2f Av[18];   float As[18];
        {
            const float4* r0 = (const float4*)(QT + (size_t)(i * TT + t) * ROWT);
            const float4* r1 = (const float4*)(QT + (size_t)(i * TT + BLOCK + t) * ROWT);
            const float4* r2 = (const float4*)(QT + (size_t)(i * TT + 2 * BLOCK + t) * ROWT);
#pragma unroll
            for (int g = 0; g < 3; ++g) {
                const float4 w0 = r0[g], w1 = r1[g], w2 = r2[g];
                Av[4*g+0].x = M2K*w0.x; Av[4*g+0].y = M2K*w1.x; As[4*g+0] = M2K*w2.x;
                Av[4*g+1].x = M2K*w0.y; Av[4*g+1].y = M2K*w1.y; As[4*g+1] = M2K*w2.y;
                Av[4*g+2].x = M2K*w0.z; Av[4*g+2].y = M2K*w1.z; As[4*g+2] = M2K*w2.z;
                Av[4*g+3].x = w0.w;     Av[4*g+3].y = w1.w;     As[4*g+3] = w2.w;
            }
            const float4 w30 = r0[3], w31 = r1[3], w32 = r2[3];
            const float4 w40 = r0[4], w41 = r1[4], w42 = r2[4];
            Av[12].x=w30.x; Av[12].y=w31.x; As[12]=w32.x;
            Av[13].x=w30.y; Av[13].y=w31.y; As[13]=w32.y;
            Av[14].x=w30.z; Av[14].y=w31.z; As[14]=w32.z;
            Av[15].x=w30.w; Av[15].y=w31.w; As[15]=w32.w;
            Av[16].x=w40.x; Av[16].y=w41.x; As[16]=w42.x;
            Av[17].x=w40.y; Av[17].y=w41.y; As[17]=w42.y;
        }

        v2f s0v = {0.f, 0.f}, s1v = s0v, s3v = s0v;
        float s0s = 0.f, s1s = 0.f, s3s = 0.f;
        const float* __restrict__ qv =
            QT + (size_t)(j * TT + chunk * MCH) * ROWT + vz;  // per-lane addr

#pragma unroll 2
        for (int m = 0; m < MCH; ++m) {
            const float4* bp = (const float4*)(qv + (size_t)m * ROWT);
            const float4 B0 = bp[0], B1 = bp[1], B2 = bp[2], B3 = bp[3], B4 = bp[4];
            const float b0=B0.x,  b1=B0.y,  b2=B0.z,  b3=B0.w;
            const float b4=B1.x,  b5=B1.y,  b6=B1.z,  b7=B1.w;
            const float b8=B2.x,  b9=B2.y,  b10=B2.z, b11=B2.w;
            const float b12=B3.x, b13=B3.y, b14=B3.z, b15=B3.w;
            const float b16=B4.x, b17=B4.y;

            v2f t11 = Av[3] + b3;
            t11 = Av[0] * b0 + t11;
            t11 = Av[1] * b1 + t11;
            t11 = Av[2] * b2 + t11;
            v2f t22 = Av[7] + b7;
            t22 = Av[4] * b4 + t22;
            t22 = Av[5] * b5 + t22;
            t22 = Av[6] * b6 + t22;
            v2f tgg = Av[11] + b11;
            tgg = Av[8]  * b8  + tgg;
            tgg = Av[9]  * b9  + tgg;
            tgg = Av[10] * b10 + tgg;
            v2f g11 = Av[12] * b12;
            g11 = Av[13] * b13 + g11;
            g11 = Av[14] * b14 + g11;
            v2f g22 = Av[15] * b15;
            g22 = Av[16] * b16 + g22;
            g22 = Av[17] * b17 + g22;

            float u11 = As[3] + b3;
            u11 = As[0] * b0 + u11;
            u11 = As[1] * b1 + u11;
            u11 = As[2] * b2 + u11;
            float u22 = As[7] + b7;
            u22 = As[4] * b4 + u22;
            u22 = As[5] * b5 + u22;
            u22 = As[6] * b6 + u22;
            float ugg = As[11] + b11;
            ugg = As[8]  * b8  + ugg;
            ugg = As[9]  * b9  + ugg;
            ugg = As[10] * b10 + ugg;
            float h11 = As[12] * b12;
            h11 = As[13] * b13 + h11;
            h11 = As[14] * b14 + h11;
            float h22 = As[15] * b15;
            h22 = As[16] * b16 + h22;
            h22 = As[17] * b17 + h22;

            v2f e11, e22, egg;
            e11.x = __builtin_amdgcn_exp2f(t11.x);
            e11.y = __builtin_amdgcn_exp2f(t11.y);
            e22.x = __builtin_amdgcn_exp2f(t22.x);
            e22.y = __builtin_amdgcn_exp2f(t22.y);
            egg.x = __builtin_amdgcn_exp2f(tgg.x);
            egg.y = __builtin_amdgcn_exp2f(tgg.y);
            const float f11 = __builtin_amdgcn_exp2f(u11);
            const float f22 = __builtin_amdgcn_exp2f(u22);
            const float fgg = __builtin_amdgcn_exp2f(ugg);

            s0v = e11 * g11 + s0v;
            s1v = e22 * g22 + s1v;
            s3v = egg * g22 + s3v;
            s0s = f11 * h11 + s0s;
            s1s = f22 * h22 + s1s;
            s3s = fgg * h22 + s3s;
        }
        const float w = (i == j) ? 1.f : 2.f;
        float r0 = w * (s0v.x + s0v.y + s0s);
        float r1 = w * (s1v.x + s1v.y + s1s);
        float r3 = w * (s3v.x + s3v.y + s3s);

#pragma unroll
        for (int off = 32; off > 0; off >>= 1) {
            r0 += __shfl_down(r0, off);
            r1 += __shfl_down(r1, off);
            r3 += __shfl_down(r3, off);
        }
        const int wave = t >> 6, lane = t & 63;
        if (lane == 0) { red[wave][0]=r0; red[wave][1]=r1; red[wave][2]=r3; }
        __syncthreads();
        if (t == 0) {
            pT[0 * NBT + tb] = red[0][0] + red[1][0];
            pT[1 * NBT + tb] = red[0][1] + red[1][1];
            pT[2 * NBT + tb] = red[0][2] + red[1][2];
        }
    }
}

__global__ __launch_bounds__(256) void finalize_kernel(
    const float* __restrict__ pT, const float* __restrict__ pF,
    float* __restrict__ out)
{
    __shared__ double red[4][5];
    double l0 = 0, l1 = 0, l2 = 0, l3 = 0, l4 = 0;
    for (int b = threadIdx.x; b < NBT; b += 256) {
        l0 += pT[0 * NBT + b];
        l1 += pT[1 * NBT + b];
        l3 += pT[2 * NBT + b];
    }
    for (int b = threadIdx.x; b < NBF; b += 256) {
        l2 += pF[0 * NBF + b];
        l4 += pF[1 * NBF + b];
    }
#pragma unroll
    for (int off = 32; off > 0; off >>= 1) {
        l0 += __shfl_down(l0, off);
        l1 += __shfl_down(l1, off);
        l2 += __shfl_down(l2, off);
        l3 += __shfl_down(l3, off);
        l4 += __shfl_down(l4, off);
    }
    const int wave = threadIdx.x >> 6, lane = threadIdx.x & 63;
    if (lane == 0) {
        red[wave][0] = l0; red[wave][1] = l1; red[wave][2] = l2;
        red[wave][3] = l3; red[wave][4] = l4;
    }
    __syncthreads();
    if (threadIdx.x == 0) {
        const double a0 = red[0][0] + red[1][0] + red[2][0] + red[3][0];
        const double a1 = red[0][1] + red[1][1] + red[2][1] + red[3][1];
        const double a2 = red[0][2] + red[1][2] + red[2][2] + red[3][2];
        const double a3 = red[0][3] + red[1][3] + red[2][3] + red[3][3];
        const double a4 = red[0][4] + red[1][4] + red[2][4] + red[3][4];
        const double num = a0 + a1 - 2.0 * a2;
        const double den = a0 + a3 - 2.0 * a4;
        out[0] = (float)(num / den);
    }
}

extern "C" void kernel_launch(void* const* d_in, const int* in_sizes, int n_in,
                              void* d_out, int out_size, void* d_ws, size_t ws_size,
                              hipStream_t stream)
{
    const float* depth1 = (const float*)d_in[0];
    const float* depth2 = (const float*)d_in[1];
    const float* pose   = (const float*)d_in[2];
    const float* img1   = (const float*)d_in[3];
    const float* img2   = (const float*)d_in[4];
    const float* poseg  = (const float*)d_in[5];

    float* QT  = (float*)d_ws;                       // 6912*20 f = 553 KB
    float* QFn = QT  + (size_t)NPTS * ROWT;          // 6912* 8 f = 221 KB
    float* QFm = QFn + (size_t)NPTS * ROWFN;         // 6912*12 f = 332 KB
    float* pT  = QFm + (size_t)NPTS * ROWFM;         // 3*1026 f
    float* pF  = pT  + 3 * NBT;                      // 2*972 f

    precompute_kernel<<<NPTS / 256, 256, 0, stream>>>(depth1, depth2, pose,
                                                      img1, img2, poseg,
                                                      QT, QFn, QFm);
    pair_kernel<<<NBLK, BLOCK, 0, stream>>>(QT, QFn, QFm, pT, pF);
    finalize_kernel<<<1, 256, 0, stream>>>(pT, pF, (float*)d_out);
}